// Round 5
// baseline (123.967 us; speedup 1.0000x reference)
//
#include <hip/hip_runtime.h>
#include <hip/hip_bf16.h>

// Chamfer distance between two (1,16384,3) fp32 clouds.
// Inner score: t = x.y - |y|^2/2 (maximized over y) => d2min = |x|^2 - 2*max_t.
// Core: 3 v_pk_fma_f32 + 1 v_max3_f32 per (1 x-point x 2 y-points) = 2 instr/pair.
// R5 fix: x held as DISTINCT packed pairs, broadcast via VOP3P op_sel, so the
// compiler cannot rematerialize splat pairs (R4: VGPR=72 + v_mov bloat -> 2.2x
// VALU). x cost: 48 VGPRs for XPT=16; total ~92 -> 4 waves/SIMD.

constexpr int P      = 16384;
constexpr int BLK    = 256;
constexpr int XPT    = 16;              // x points per thread
constexpr int XCHUNK = BLK * XPT;       // 4096 -> grid.x = 4

typedef float v2f __attribute__((ext_vector_type(2)));

// t = broadcast(lo half of xp) * y + c
static __device__ inline v2f pk_fma_lo(v2f xp, v2f y, v2f c) {
    v2f d;
    asm("v_pk_fma_f32 %0, %1, %2, %3 op_sel:[0,0,0] op_sel_hi:[0,1,1]"
        : "=v"(d) : "v"(xp), "v"(y), "v"(c));
    return d;
}
// t = broadcast(hi half of xp) * y + c
static __device__ inline v2f pk_fma_hi(v2f xp, v2f y, v2f c) {
    v2f d;
    asm("v_pk_fma_f32 %0, %1, %2, %3 op_sel:[1,0,0] op_sel_hi:[1,1,1]"
        : "=v"(d) : "v"(xp), "v"(y), "v"(c));
    return d;
}
static __device__ inline float max3(float a, float b, float c) {
    float d;
    asm("v_max3_f32 %0, %1, %2, %3" : "=v"(d) : "v"(a), "v"(b), "v"(c));
    return d;
}

// ---------------- main: per-(dir, y-segment) partial max of t ----------------
template <int YSPLIT>
__global__ __launch_bounds__(BLK, 4) void chamfer_main(
    const float* __restrict__ pc1, const float* __restrict__ pc2,
    float* __restrict__ partial,    // [2][YSPLIT][P] of max_t
    float* __restrict__ out)        // zeroed here (reduce atomicAdds later)
{
    constexpr int YSEG = P / YSPLIT;    // y per segment (128 or 256)
    constexpr int NGRP = YSEG / 2;      // y-pair groups of 8 floats

    if (blockIdx.x == 0 && blockIdx.y == 0 && blockIdx.z == 0 && threadIdx.x == 0)
        out[0] = 0.0f;

    const int dir = blockIdx.z;
    const float* xs = dir ? pc2 : pc1;
    const float* ys = dir ? pc1 : pc2;

    // ---- stage y segment into LDS, interleaved pair-groups:
    //      group g = { x0,x1, y0,y1, z0,z1, w0,w1 }  (w = -|y|^2/2)
    //      lane-pair shuffle -> each thread writes ONE float4 (conflict-free).
    __shared__ __align__(16) float yt[NGRP * 8];
    {
        const int j = threadIdx.x;
        if (j < YSEG) {
            const int q = blockIdx.y * YSEG + j;
            const float a = ys[3 * q], b = ys[3 * q + 1], c = ys[3 * q + 2];
            const float w = -0.5f * fmaf(a, a, fmaf(b, b, c * c));
            const float a2 = __shfl_xor(a, 1, 64);
            const float b2 = __shfl_xor(b, 1, 64);
            const float c2 = __shfl_xor(c, 1, 64);
            const float w2 = __shfl_xor(w, 1, 64);
            const float4 v = (j & 1) ? make_float4(c2, c, w2, w)
                                     : make_float4(a, a2, b, b2);
            ((float4*)yt)[j] = v;
        }
    }

    // ---- per-thread x points, packed as DISTINCT pairs (op_sel broadcasts):
    //      xa[k] = (x0_k, x1_k); xb[m] = (x2_{2m}, x2_{2m+1})
    const int p0 = blockIdx.x * XCHUNK + threadIdx.x;
    v2f xa[XPT];
    v2f xb[XPT / 2];
    float acc[XPT];
    #pragma unroll
    for (int k = 0; k < XPT; ++k) {
        const int p = p0 + k * BLK;
        const float a = xs[3 * p], b = xs[3 * p + 1], c = xs[3 * p + 2];
        xa[k] = (v2f){a, b};
        if (k & 1) xb[k >> 1].y = c; else xb[k >> 1].x = c;
        acc[k] = -3.0e38f;
    }
    __syncthreads();

    // ---- inner loop: 2 broadcast ds_read_b128 (double-buffered) +
    //      XPT x (3 v_pk_fma_f32 + 1 v_max3_f32) per y-pair group ----
    const float4* gptr = (const float4*)yt;
    float4 A = gptr[0], B = gptr[1];
    #pragma unroll 2
    for (int g = 0; g < NGRP; ++g) {
        const int gn = (2 * g + 2) & (2 * NGRP - 1);   // masked wrap: branch-free
        const float4 An = gptr[gn];
        const float4 Bn = gptr[gn + 1];
        const v2f y0 = {A.x, A.y};
        const v2f y1 = {A.z, A.w};
        const v2f y2 = {B.x, B.y};
        const v2f yw = {B.z, B.w};
        #pragma unroll
        for (int k = 0; k < XPT; ++k) {
            v2f t = pk_fma_lo(xa[k], y0, yw);                       // x0*y0 + yw
            t = pk_fma_hi(xa[k], y1, t);                            // + x1*y1
            t = (k & 1) ? pk_fma_hi(xb[k >> 1], y2, t)              // + x2*y2
                        : pk_fma_lo(xb[k >> 1], y2, t);
            acc[k] = max3(acc[k], t.x, t.y);
        }
        A = An; B = Bn;
    }

    float* pout = partial + ((size_t)dir * YSPLIT + blockIdx.y) * P;
    #pragma unroll
    for (int k = 0; k < XPT; ++k) pout[p0 + k * BLK] = acc[k];
}

// ---------------- reduce: max over segments, d2, threshold, mean, atomic ----
template <int YSPLIT>
__global__ __launch_bounds__(BLK) void chamfer_reduce(
    const float* __restrict__ partial,
    const float* __restrict__ pc1, const float* __restrict__ pc2,
    float* __restrict__ out)
{
    const int gid = blockIdx.x * BLK + threadIdx.x;   // 0 .. 2P-1
    const int dir = (gid >= P) ? 1 : 0;
    const int p = gid & (P - 1);
    const float* xsrc = dir ? pc2 : pc1;
    const float* base = partial + (size_t)dir * YSPLIT * P + p;

    float M = base[0];
    #pragma unroll 8
    for (int s = 1; s < YSPLIT; ++s) M = fmaxf(M, base[(size_t)s * P]);

    const float a = xsrc[3 * p], b = xsrc[3 * p + 1], c = xsrc[3 * p + 2];
    const float xx = fmaf(a, a, fmaf(b, b, c * c));
    float d2 = fmaf(-2.0f, M, xx);                    // |x|^2 - 2*max_t
    if (d2 >= 2.0f) d2 = 0.0f;                        // DIST_THD mask
    float v = d2 * (1.0f / (float)P);                 // mean over points; N=1

    #pragma unroll
    for (int off = 32; off > 0; off >>= 1) v += __shfl_down(v, off, 64);

    __shared__ float wsum[BLK / 64];
    const int lane = threadIdx.x & 63;
    const int wv = threadIdx.x >> 6;
    if (lane == 0) wsum[wv] = v;
    __syncthreads();
    if (threadIdx.x == 0) {
        float s = wsum[0];
        #pragma unroll
        for (int w = 1; w < BLK / 64; ++w) s += wsum[w];
        atomicAdd(out, s);
    }
}

extern "C" void kernel_launch(void* const* d_in, const int* in_sizes, int n_in,
                              void* d_out, int out_size, void* d_ws, size_t ws_size,
                              hipStream_t stream) {
    const float* pc1 = (const float*)d_in[0];
    const float* pc2 = (const float*)d_in[1];
    float* out = (float*)d_out;
    float* partial = (float*)d_ws;

    // Prefer YSPLIT=128 (1024 blocks = 4/CU); needs 16.8 MB of ws for partial.
    if (ws_size >= (size_t)2 * 128 * P * sizeof(float)) {
        dim3 grid(P / XCHUNK, 128, 2);
        chamfer_main<128><<<grid, BLK, 0, stream>>>(pc1, pc2, partial, out);
        chamfer_reduce<128><<<(2 * P) / BLK, BLK, 0, stream>>>(partial, pc1, pc2, out);
    } else {
        dim3 grid(P / XCHUNK, 64, 2);
        chamfer_main<64><<<grid, BLK, 0, stream>>>(pc1, pc2, partial, out);
        chamfer_reduce<64><<<(2 * P) / BLK, BLK, 0, stream>>>(partial, pc1, pc2, out);
    }
}

// Round 6
// 100.540 us; speedup vs baseline: 1.2330x; 1.2330x over previous
//
#include <hip/hip_runtime.h>
#include <hip/hip_bf16.h>

// Chamfer distance between two (1,16384,3) fp32 clouds.
// Inner score: t = x.y - |y|^2/2 (maximized over y) => d2min = |x|^2 - 2*max_t.
// Core: 3 v_pk_fma_f32 (op_sel broadcast) + 1 v_max3_f32 per (1x x 2y).
// R6: (1) asm keep-alives pin x in VGPRs (R5: compiler sank x loads into the
// loop, VGPR=40); (2) per-point result via atomicMax on order-encoded fp32
// (exact, commutative) into [2][P] uints -- kills the 16.8MB partial array;
// (3) 2048 blocks = 8 waves/SIMD for latency hiding.

constexpr int P      = 16384;
constexpr int BLK    = 256;
constexpr int XPT    = 16;              // x points per thread
constexpr int XCHUNK = BLK * XPT;       // 4096 -> grid.x = 4
constexpr int YSPLIT = 256;             // grid 4*256*2 = 2048 blocks (8/CU)
constexpr int YSEG   = P / YSPLIT;      // 64 y per segment
constexpr int NGRP   = YSEG / 2;        // 32 y-pair groups of 8 floats

typedef float v2f __attribute__((ext_vector_type(2)));

// t = broadcast(lo half of xp) * y + c
static __device__ inline v2f pk_fma_lo(v2f xp, v2f y, v2f c) {
    v2f d;
    asm("v_pk_fma_f32 %0, %1, %2, %3 op_sel:[0,0,0] op_sel_hi:[0,1,1]"
        : "=v"(d) : "v"(xp), "v"(y), "v"(c));
    return d;
}
// t = broadcast(hi half of xp) * y + c
static __device__ inline v2f pk_fma_hi(v2f xp, v2f y, v2f c) {
    v2f d;
    asm("v_pk_fma_f32 %0, %1, %2, %3 op_sel:[1,0,0] op_sel_hi:[1,1,1]"
        : "=v"(d) : "v"(xp), "v"(y), "v"(c));
    return d;
}
static __device__ inline float max3(float a, float b, float c) {
    float d;
    asm("v_max3_f32 %0, %1, %2, %3" : "=v"(d) : "v"(a), "v"(b), "v"(c));
    return d;
}

// Order-preserving fp32 <-> uint32 (for exact atomicMax on floats).
static __device__ inline unsigned enc_f32(float f) {
    unsigned b = __float_as_uint(f);
    return (b & 0x80000000u) ? ~b : (b | 0x80000000u);
}
static __device__ inline float dec_f32(unsigned u) {
    unsigned b = (u & 0x80000000u) ? (u & 0x7FFFFFFFu) : ~u;
    return __uint_as_float(b);
}

// ---------------- main: atomicMax of encoded t into part[2][P] ---------------
__global__ __launch_bounds__(BLK, 4) void chamfer_main(
    const float* __restrict__ pc1, const float* __restrict__ pc2,
    unsigned* __restrict__ part,    // [2][P], pre-zeroed (0 < enc of any real t)
    float* __restrict__ out)        // zeroed here (reduce atomicAdds later)
{
    if (blockIdx.x == 0 && blockIdx.y == 0 && blockIdx.z == 0 && threadIdx.x == 0)
        out[0] = 0.0f;

    const int dir = blockIdx.z;
    const float* xs = dir ? pc2 : pc1;
    const float* ys = dir ? pc1 : pc2;

    // ---- stage y segment into LDS, interleaved pair-groups:
    //      group g = { x0,x1, y0,y1, z0,z1, w0,w1 }  (w = -|y|^2/2)
    //      lane-pair shuffle -> each staging thread writes ONE float4.
    __shared__ __align__(16) float yt[NGRP * 8];
    {
        const int j = threadIdx.x;
        if (j < YSEG) {
            const int q = blockIdx.y * YSEG + j;
            const float a = ys[3 * q], b = ys[3 * q + 1], c = ys[3 * q + 2];
            const float w = -0.5f * fmaf(a, a, fmaf(b, b, c * c));
            const float a2 = __shfl_xor(a, 1, 64);
            const float b2 = __shfl_xor(b, 1, 64);
            const float c2 = __shfl_xor(c, 1, 64);
            const float w2 = __shfl_xor(w, 1, 64);
            const float4 v = (j & 1) ? make_float4(c2, c, w2, w)
                                     : make_float4(a, a2, b, b2);
            ((float4*)yt)[j] = v;
        }
    }

    // ---- per-thread x points, packed as DISTINCT pairs (op_sel broadcasts):
    //      xa[k] = (x0_k, x1_k); xb[m] = (x2_{2m}, x2_{2m+1})
    const int p0 = blockIdx.x * XCHUNK + threadIdx.x;
    v2f xa[XPT];
    v2f xb[XPT / 2];
    float acc[XPT];
    #pragma unroll
    for (int k = 0; k < XPT; ++k) {
        const int p = p0 + k * BLK;
        const float a = xs[3 * p], b = xs[3 * p + 1], c = xs[3 * p + 2];
        xa[k] = (v2f){a, b};
        if (k & 1) xb[k >> 1].y = c; else xb[k >> 1].x = c;
        acc[k] = -3.0e38f;
    }
    // Pin x in VGPRs: values that flow through an asm tie cannot be
    // rematerialized or have their loads sunk into the loop (R5 failure mode).
    #pragma unroll
    for (int k = 0; k < XPT; ++k) asm volatile("" : "+v"(xa[k]));
    #pragma unroll
    for (int m = 0; m < XPT / 2; ++m) asm volatile("" : "+v"(xb[m]));
    __syncthreads();

    // ---- inner loop: 2 broadcast ds_read_b128 +
    //      XPT x (3 v_pk_fma_f32 + 1 v_max3_f32) per y-pair group ----
    const float4* gptr = (const float4*)yt;
    #pragma unroll 2
    for (int g = 0; g < NGRP; ++g) {
        const float4 A = gptr[2 * g];           // x0,x1,y0,y1
        const float4 B = gptr[2 * g + 1];       // z0,z1,w0,w1
        const v2f y0 = {A.x, A.y};
        const v2f y1 = {A.z, A.w};
        const v2f y2 = {B.x, B.y};
        const v2f yw = {B.z, B.w};
        #pragma unroll
        for (int k = 0; k < XPT; ++k) {
            v2f t = pk_fma_lo(xa[k], y0, yw);                       // x0*y0 + yw
            t = pk_fma_hi(xa[k], y1, t);                            // + x1*y1
            t = (k & 1) ? pk_fma_hi(xb[k >> 1], y2, t)              // + x2*y2
                        : pk_fma_lo(xb[k >> 1], y2, t);
            acc[k] = max3(acc[k], t.x, t.y);
        }
    }

    unsigned* pout = part + (size_t)dir * P;
    #pragma unroll
    for (int k = 0; k < XPT; ++k)
        atomicMax(&pout[p0 + k * BLK], enc_f32(acc[k]));
}

// ---------------- reduce: decode, d2, threshold, mean, atomic sum -----------
__global__ __launch_bounds__(BLK) void chamfer_reduce(
    const unsigned* __restrict__ part,
    const float* __restrict__ pc1, const float* __restrict__ pc2,
    float* __restrict__ out)
{
    const int gid = blockIdx.x * BLK + threadIdx.x;   // 0 .. 2P-1
    const int dir = (gid >= P) ? 1 : 0;
    const int p = gid & (P - 1);
    const float* xsrc = dir ? pc2 : pc1;

    const float M = dec_f32(part[(size_t)dir * P + p]);
    const float a = xsrc[3 * p], b = xsrc[3 * p + 1], c = xsrc[3 * p + 2];
    const float xx = fmaf(a, a, fmaf(b, b, c * c));
    float d2 = fmaf(-2.0f, M, xx);                    // |x|^2 - 2*max_t
    if (d2 >= 2.0f) d2 = 0.0f;                        // DIST_THD mask
    float v = d2 * (1.0f / (float)P);                 // mean over points; N=1

    #pragma unroll
    for (int off = 32; off > 0; off >>= 1) v += __shfl_down(v, off, 64);

    __shared__ float wsum[BLK / 64];
    const int lane = threadIdx.x & 63;
    const int wv = threadIdx.x >> 6;
    if (lane == 0) wsum[wv] = v;
    __syncthreads();
    if (threadIdx.x == 0) {
        float s = wsum[0];
        #pragma unroll
        for (int w = 1; w < BLK / 64; ++w) s += wsum[w];
        atomicAdd(out, s);
    }
}

extern "C" void kernel_launch(void* const* d_in, const int* in_sizes, int n_in,
                              void* d_out, int out_size, void* d_ws, size_t ws_size,
                              hipStream_t stream) {
    const float* pc1 = (const float*)d_in[0];
    const float* pc2 = (const float*)d_in[1];
    float* out = (float*)d_out;
    unsigned* part = (unsigned*)d_ws;                 // [2][P] = 128 KB

    // enc(x) > 0 for every finite float, so zero-init loses to any real t.
    hipMemsetAsync(d_ws, 0, (size_t)2 * P * sizeof(unsigned), stream);

    dim3 grid(P / XCHUNK, YSPLIT, 2);                 // 4 x 256 x 2 = 2048 blocks
    chamfer_main<<<grid, BLK, 0, stream>>>(pc1, pc2, part, out);
    chamfer_reduce<<<(2 * P) / BLK, BLK, 0, stream>>>(part, pc1, pc2, out);
}

// Round 7
// 84.183 us; speedup vs baseline: 1.4726x; 1.1943x over previous
//
#include <hip/hip_runtime.h>
#include <hip/hip_bf16.h>

// Chamfer distance between two (1,16384,3) fp32 clouds, via split-bf16
// augmented GEMM on the matrix cores:
//   A_enc[p] . B_enc[q] = |x_p|^2 + |y_q|^2 - 2 x_p.y_q = d^2(p,q)   (err ~3e-5)
// K=16 slots: [ah0,al0,ah1,al1,ah2,al2,ah0,ah1,ah2,sh,sl,1,1,0,0,0] (A side)
//             [Ah0,Ah0,Ah1,Ah1,Ah2,Ah2,Al0,Al1,Al2,1,1,sh,sl,0,0,0] (B side,
//              Ah=-2*bf16hi, Al=-2*bf16lo -- exact scalings)
// One v_mfma_f32_32x32x16_bf16 = 1024 d^2 entries; min-accumulate in C regs.

constexpr int P      = 16384;
constexpr int BLK    = 256;
constexpr int NSEG   = 8;             // column segments per direction
constexpr int SEGPTS = P / NSEG;      // 2048 cols per block
constexpr int ROUND  = 1024;          // points staged per 32 KB LDS round
constexpr int TILES  = ROUND / 32;    // 32 MFMA col-tiles per round
constexpr int ROWSB  = 256;           // rows per block (4 waves x 64)

typedef short s8v  __attribute__((ext_vector_type(8)));
typedef float f16v __attribute__((ext_vector_type(16)));

static __device__ inline unsigned short bf16r(float f) {   // RNE fp32->bf16
    unsigned u = __float_as_uint(f);
    u = (u + 0x7FFFu + ((u >> 16) & 1u)) >> 16;
    return (unsigned short)u;
}
static __device__ inline float bf2f(unsigned short h) {
    return __uint_as_float(((unsigned)h) << 16);
}

// A-side encoding, packed as 8 uints (16 bf16 slots, little-end first).
static __device__ inline void encA(float a, float b, float c, unsigned e[8]) {
    const unsigned ONE = 0x3F80u;
    const float s = fmaf(a, a, fmaf(b, b, c * c));
    const unsigned short ah = bf16r(a), bh = bf16r(b), ch = bf16r(c);
    const unsigned short al = bf16r(a - bf2f(ah));
    const unsigned short bl = bf16r(b - bf2f(bh));
    const unsigned short cl = bf16r(c - bf2f(ch));
    const unsigned short sh = bf16r(s), sl = bf16r(s - bf2f(sh));
    e[0] = ah | ((unsigned)al << 16);   // k0,k1
    e[1] = bh | ((unsigned)bl << 16);   // k2,k3
    e[2] = ch | ((unsigned)cl << 16);   // k4,k5
    e[3] = ah | ((unsigned)bh << 16);   // k6,k7
    e[4] = ch | ((unsigned)sh << 16);   // k8,k9
    e[5] = sl | (ONE << 16);            // k10,k11
    e[6] = ONE;                         // k12,k13(=0)
    e[7] = 0;                           // k14,k15
}

// B-side encoding (-2 folded in; all scalings exact in bf16).
static __device__ inline void encB(float a, float b, float c, unsigned e[8]) {
    const unsigned ONE = 0x3F80u;
    const float s = fmaf(a, a, fmaf(b, b, c * c));
    const unsigned short ah = bf16r(a), bh = bf16r(b), ch = bf16r(c);
    const unsigned short al = bf16r(a - bf2f(ah));
    const unsigned short bl = bf16r(b - bf2f(bh));
    const unsigned short cl = bf16r(c - bf2f(ch));
    const unsigned short sh = bf16r(s), sl = bf16r(s - bf2f(sh));
    const unsigned short Ah = bf16r(-2.f * bf2f(ah)), Bh = bf16r(-2.f * bf2f(bh));
    const unsigned short Ch = bf16r(-2.f * bf2f(ch));
    const unsigned short Al = bf16r(-2.f * bf2f(al)), Bl = bf16r(-2.f * bf2f(bl));
    const unsigned short Cl = bf16r(-2.f * bf2f(cl));
    e[0] = Ah | ((unsigned)Ah << 16);   // k0,k1
    e[1] = Bh | ((unsigned)Bh << 16);   // k2,k3
    e[2] = Ch | ((unsigned)Ch << 16);   // k4,k5
    e[3] = Al | ((unsigned)Bl << 16);   // k6,k7
    e[4] = Cl | (ONE << 16);            // k8,k9
    e[5] = ONE | ((unsigned)sh << 16);  // k10,k11
    e[6] = sl;                          // k12,k13(=0)
    e[7] = 0;                           // k14,k15
}

// ---- main: per (rowgroup, segment, dir) strip-sweep GEMM with min-acc ------
__global__ __launch_bounds__(BLK, 4) void chamfer_mfma(
    const float* __restrict__ pc1, const float* __restrict__ pc2,
    float* __restrict__ part,       // [2][NSEG][P], every slot written once
    float* __restrict__ out)
{
    if (blockIdx.x == 0 && blockIdx.y == 0 && blockIdx.z == 0 && threadIdx.x == 0)
        out[0] = 0.0f;

    const int dir = blockIdx.z;
    const float* xs = dir ? pc2 : pc1;   // rows (queries)
    const float* ys = dir ? pc1 : pc2;   // cols (swept)

    __shared__ __align__(16) unsigned char ytile[ROUND * 32];  // 32 KB

    const int tid  = threadIdx.x;
    const int lane = tid & 63;
    const int wv   = tid >> 6;
    const int l31  = lane & 31;
    const int half = lane >> 5;          // k-half for A/B frags

    // ---- A fragments: 2 strips of 32 rows per wave, built once ----
    const int rowbase = blockIdx.x * ROWSB + wv * 64;
    s8v afrag[2];
    #pragma unroll
    for (int s = 0; s < 2; ++s) {
        const int p = rowbase + s * 32 + l31;
        unsigned e[8];
        encA(xs[3 * p], xs[3 * p + 1], xs[3 * p + 2], e);
        union { uint4 i; s8v v; } lo, hi;
        lo.i = make_uint4(e[0], e[1], e[2], e[3]);
        hi.i = make_uint4(e[4], e[5], e[6], e[7]);
        afrag[s] = half ? hi.v : lo.v;
    }

    f16v acc0, acc1, Z;
    #pragma unroll
    for (int i = 0; i < 16; ++i) { acc0[i] = 3.0e38f; acc1[i] = 3.0e38f; Z[i] = 0.0f; }

    const int segbase = blockIdx.y * SEGPTS;
    for (int r = 0; r < SEGPTS / ROUND; ++r) {
        // ---- stage ROUND col-points, swizzled so B-frag read is lane-linear:
        //      tile tt, col cc, half h  ->  ytile[tt*1024 + h*512 + cc*16]
        #pragma unroll 2
        for (int j = 0; j < ROUND / BLK; ++j) {
            const int i = tid + j * BLK;
            const int q = segbase + r * ROUND + i;
            unsigned e[8];
            encB(ys[3 * q], ys[3 * q + 1], ys[3 * q + 2], e);
            const int tt = i >> 5, cc = i & 31;
            *(uint4*)(ytile + tt * 1024 +       cc * 16) = make_uint4(e[0], e[1], e[2], e[3]);
            *(uint4*)(ytile + tt * 1024 + 512 + cc * 16) = make_uint4(e[4], e[5], e[6], e[7]);
        }
        __syncthreads();

        const unsigned char* rp = ytile + lane * 16;   // conflict-free b128
        #pragma unroll 2
        for (int t = 0; t < TILES; ++t) {
            const s8v bfrag = *(const s8v*)(rp + t * 1024);
            const f16v d0 = __builtin_amdgcn_mfma_f32_32x32x16_bf16(afrag[0], bfrag, Z, 0, 0, 0);
            acc0 = __builtin_elementwise_min(acc0, d0);
            const f16v d1 = __builtin_amdgcn_mfma_f32_32x32x16_bf16(afrag[1], bfrag, Z, 0, 0, 0);
            acc1 = __builtin_elementwise_min(acc1, d1);
        }
        __syncthreads();
    }

    // ---- fold over the 32 columns held across lanes; write per-row min ----
    // C/D layout (verified): col=lane&31, row=(reg&3)+8*(reg>>2)+4*(lane>>5)
    float* pbase = part + ((size_t)(dir * NSEG + blockIdx.y)) * P;
    #pragma unroll
    for (int s = 0; s < 2; ++s) {
        #pragma unroll
        for (int rg = 0; rg < 16; ++rg) {
            float v = s ? acc1[rg] : acc0[rg];
            v = fminf(v, __shfl_xor(v, 1, 64));
            v = fminf(v, __shfl_xor(v, 2, 64));
            v = fminf(v, __shfl_xor(v, 4, 64));
            v = fminf(v, __shfl_xor(v, 8, 64));
            v = fminf(v, __shfl_xor(v, 16, 64));
            if (l31 == 0) {
                const int row = rowbase + s * 32 + (rg & 3) + 8 * (rg >> 2) + 4 * half;
                pbase[row] = v;
            }
        }
    }
}

// ---- reduce: min over segments, threshold, mean, atomic sum ----------------
__global__ __launch_bounds__(BLK) void chamfer_reduce(
    const float* __restrict__ part, float* __restrict__ out)
{
    const int gid = blockIdx.x * BLK + threadIdx.x;   // 0 .. 2P-1
    const int dirbase = (gid >= P) ? NSEG * P : 0;
    const int row = gid & (P - 1);

    float m = part[dirbase + row];
    #pragma unroll
    for (int s = 1; s < NSEG; ++s) m = fminf(m, part[dirbase + s * P + row]);

    if (m >= 2.0f) m = 0.0f;                  // DIST_THD mask
    float v = m * (1.0f / (float)P);          // point mean; batch N=1

    #pragma unroll
    for (int off = 32; off > 0; off >>= 1) v += __shfl_down(v, off, 64);

    __shared__ float wsum[BLK / 64];
    const int lane = threadIdx.x & 63;
    const int wvi = threadIdx.x >> 6;
    if (lane == 0) wsum[wvi] = v;
    __syncthreads();
    if (threadIdx.x == 0) {
        float ssum = wsum[0];
        #pragma unroll
        for (int w = 1; w < BLK / 64; ++w) ssum += wsum[w];
        atomicAdd(out, ssum);
    }
}

extern "C" void kernel_launch(void* const* d_in, const int* in_sizes, int n_in,
                              void* d_out, int out_size, void* d_ws, size_t ws_size,
                              hipStream_t stream) {
    const float* pc1 = (const float*)d_in[0];
    const float* pc2 = (const float*)d_in[1];
    float* out = (float*)d_out;
    float* part = (float*)d_ws;               // [2][NSEG][P] = 1 MB

    dim3 grid(P / ROWSB, NSEG, 2);            // 64 x 8 x 2 = 1024 blocks
    chamfer_mfma<<<grid, BLK, 0, stream>>>(pc1, pc2, part, out);
    chamfer_reduce<<<(2 * P) / BLK, BLK, 0, stream>>>(part, out);
}